// Round 1
// baseline (161.501 us; speedup 1.0000x reference)
//
#include <hip/hip_runtime.h>

#define IN_CH   32
#define OUT_CH  64
#define NFILT   16
#define BATCH   32
#define HW      50176     // 224*224
#define HW4     12544     // HW/4 (float4 elements per plane)
#define CHUNKS  49        // HW4 / 256

// ---------------------------------------------------------------------------
// Kernel 1: global average pool. One block per (b, c) pair; float4 loads,
// shuffle + LDS reduce.
// ---------------------------------------------------------------------------
__global__ __launch_bounds__(256) void pool_kernel(const float* __restrict__ x,
                                                   float* __restrict__ pooled) {
    const int bc = blockIdx.x;  // 0 .. BATCH*IN_CH-1
    const float4* xp = reinterpret_cast<const float4*>(x) + (size_t)bc * HW4;

    float4 s = make_float4(0.f, 0.f, 0.f, 0.f);
    for (int i = threadIdx.x; i < HW4; i += 256) {
        float4 v = xp[i];
        s.x += v.x; s.y += v.y; s.z += v.z; s.w += v.w;
    }
    float sum = (s.x + s.y) + (s.z + s.w);

    // wave-64 butterfly reduce
    for (int off = 32; off > 0; off >>= 1)
        sum += __shfl_down(sum, off, 64);

    __shared__ float red[4];
    const int wid  = threadIdx.x >> 6;
    if ((threadIdx.x & 63) == 0) red[wid] = sum;
    __syncthreads();
    if (threadIdx.x == 0) {
        float t = (red[0] + red[1]) + (red[2] + red[3]);
        pooled[bc] = t * (1.0f / (float)HW);
    }
}

// ---------------------------------------------------------------------------
// Kernel 2: router logits + top-16 mask. One block (64 threads) per sample.
// Tie-break matches jax.lax.top_k: strictly greater, or equal with lower idx.
// ---------------------------------------------------------------------------
__global__ __launch_bounds__(64) void router_kernel(const float* __restrict__ pooled,
                                                    const float* __restrict__ rw,
                                                    const float* __restrict__ rb,
                                                    float* __restrict__ mask) {
    const int b = blockIdx.x;
    const int o = threadIdx.x;

    __shared__ float lg[OUT_CH];

    float acc = rb[o];
    #pragma unroll
    for (int c = 0; c < IN_CH; ++c)
        acc += pooled[b * IN_CH + c] * rw[o * IN_CH + c];
    lg[o] = acc;
    __syncthreads();

    int rank = 0;
    #pragma unroll
    for (int j = 0; j < OUT_CH; ++j) {
        float lj = lg[j];
        rank += (lj > acc) || (lj == acc && j < o);
    }
    mask[b * OUT_CH + o] = (rank < NFILT) ? 1.0f : 0.0f;
}

// ---------------------------------------------------------------------------
// Kernel 3: 1x1 conv + bias, gated by mask. Each thread owns one float4
// pixel for one sample: loads all 32 input channels into registers, then
// loops over the 64 output channels. Masked-off channels store zeros and
// skip the FMAs (branch is uniform across the block: mask depends on (b,o)).
// ---------------------------------------------------------------------------
__global__ __launch_bounds__(256) void conv_kernel(const float* __restrict__ x,
                                                   const float* __restrict__ weight,
                                                   const float* __restrict__ bias,
                                                   const float* __restrict__ mask,
                                                   float* __restrict__ out) {
    __shared__ float w_s[OUT_CH][IN_CH];
    __shared__ float b_s[OUT_CH];
    __shared__ float m_s[OUT_CH];

    const int b     = blockIdx.x / CHUNKS;
    const int chunk = blockIdx.x % CHUNKS;

    for (int i = threadIdx.x; i < OUT_CH * IN_CH; i += 256)
        (&w_s[0][0])[i] = weight[i];
    if (threadIdx.x < OUT_CH) {
        b_s[threadIdx.x] = bias[threadIdx.x];
        m_s[threadIdx.x] = mask[b * OUT_CH + threadIdx.x];
    }
    __syncthreads();

    const int pos = chunk * 256 + threadIdx.x;
    const float4* x4  = reinterpret_cast<const float4*>(x);
    float4*       o4  = reinterpret_cast<float4*>(out);

    float4 xv[IN_CH];
    #pragma unroll
    for (int c = 0; c < IN_CH; ++c)
        xv[c] = x4[(size_t)(b * IN_CH + c) * HW4 + pos];

    for (int o = 0; o < OUT_CH; ++o) {
        float4 r;
        if (m_s[o] != 0.0f) {
            const float bv = b_s[o];
            r = make_float4(bv, bv, bv, bv);
            #pragma unroll
            for (int c = 0; c < IN_CH; ++c) {
                const float w = w_s[o][c];
                r.x += w * xv[c].x;
                r.y += w * xv[c].y;
                r.z += w * xv[c].z;
                r.w += w * xv[c].w;
            }
        } else {
            r = make_float4(0.f, 0.f, 0.f, 0.f);
        }
        o4[(size_t)(b * OUT_CH + o) * HW4 + pos] = r;
    }
}

// ---------------------------------------------------------------------------
extern "C" void kernel_launch(void* const* d_in, const int* in_sizes, int n_in,
                              void* d_out, int out_size, void* d_ws, size_t ws_size,
                              hipStream_t stream) {
    const float* x    = (const float*)d_in[0];
    const float* w    = (const float*)d_in[1];
    const float* bias = (const float*)d_in[2];
    const float* rw   = (const float*)d_in[3];
    const float* rb   = (const float*)d_in[4];
    float* out = (float*)d_out;

    float* pooled = (float*)d_ws;                    // BATCH*IN_CH floats
    float* mask   = pooled + BATCH * IN_CH;          // BATCH*OUT_CH floats

    pool_kernel<<<BATCH * IN_CH, 256, 0, stream>>>(x, pooled);
    router_kernel<<<BATCH, 64, 0, stream>>>(pooled, rw, rb, mask);
    conv_kernel<<<BATCH * CHUNKS, 256, 0, stream>>>(x, w, bias, mask, out);
}

// Round 3
// 126.550 us; speedup vs baseline: 1.2762x; 1.2762x over previous
//
#include <hip/hip_runtime.h>

#define IN_CH   32
#define OUT_CH  64
#define NFILT   16
#define BATCH   32
#define HW      50176     // 224*224
#define HW4     12544     // HW/4 (float4 elements per plane)
#define CHUNKS  49        // HW4 / 256

typedef float vfloat4 __attribute__((ext_vector_type(4)));  // native vec for nt-store

// ---------------------------------------------------------------------------
// Kernel 1: global average pool. One block per (b, c) pair; float4 loads,
// shuffle + LDS reduce. Normal (caching) loads on purpose: this pass pulls
// x into the 256 MB Infinity Cache so the conv pass re-reads it from L3.
// ---------------------------------------------------------------------------
__global__ __launch_bounds__(256) void pool_kernel(const float* __restrict__ x,
                                                   float* __restrict__ pooled) {
    const int bc = blockIdx.x;  // 0 .. BATCH*IN_CH-1
    const float4* xp = reinterpret_cast<const float4*>(x) + (size_t)bc * HW4;

    float4 s = make_float4(0.f, 0.f, 0.f, 0.f);
    for (int i = threadIdx.x; i < HW4; i += 256) {
        float4 v = xp[i];
        s.x += v.x; s.y += v.y; s.z += v.z; s.w += v.w;
    }
    float sum = (s.x + s.y) + (s.z + s.w);

    // wave-64 butterfly reduce
    for (int off = 32; off > 0; off >>= 1)
        sum += __shfl_down(sum, off, 64);

    __shared__ float red[4];
    const int wid = threadIdx.x >> 6;
    if ((threadIdx.x & 63) == 0) red[wid] = sum;
    __syncthreads();
    if (threadIdx.x == 0) {
        float t = (red[0] + red[1]) + (red[2] + red[3]);
        pooled[bc] = t * (1.0f / (float)HW);
    }
}

// ---------------------------------------------------------------------------
// Kernel 2: fused router + 1x1 conv + bias + gate.
// Preamble (threads 0..63): router logits from pooled -> rank-based top-16
// mask (tie-break matches jax.lax.top_k: strictly greater, or equal with
// lower index). Redundant across the 49 blocks of a sample — deterministic
// and ~2048 FMAs, i.e. free.
// Body: each thread owns one float4 pixel; all 32 input channels in
// registers; loop over 64 output channels, skipping FMAs for masked-off
// channels (wave-uniform branch). Stores are NON-TEMPORAL so the 411 MB
// output stream does not evict x from Infinity Cache.
// ---------------------------------------------------------------------------
__global__ __launch_bounds__(256) void conv_kernel(const float* __restrict__ x,
                                                   const float* __restrict__ weight,
                                                   const float* __restrict__ bias,
                                                   const float* __restrict__ rw,
                                                   const float* __restrict__ rb,
                                                   const float* __restrict__ pooled,
                                                   float* __restrict__ out) {
    __shared__ float w_s[OUT_CH][IN_CH];
    __shared__ float b_s[OUT_CH];
    __shared__ float lg[OUT_CH];
    __shared__ float m_s[OUT_CH];

    const int b     = blockIdx.x / CHUNKS;
    const int chunk = blockIdx.x % CHUNKS;

    // stage weights/bias
    for (int i = threadIdx.x; i < OUT_CH * IN_CH; i += 256)
        (&w_s[0][0])[i] = weight[i];

    // router logits (threads 0..63)
    if (threadIdx.x < OUT_CH) {
        const int o = threadIdx.x;
        b_s[o] = bias[o];
        float acc = rb[o];
        #pragma unroll
        for (int c = 0; c < IN_CH; ++c)
            acc += pooled[b * IN_CH + c] * rw[o * IN_CH + c];
        lg[o] = acc;
    }
    __syncthreads();

    // rank -> mask
    if (threadIdx.x < OUT_CH) {
        const int o = threadIdx.x;
        const float acc = lg[o];
        int rank = 0;
        #pragma unroll
        for (int j = 0; j < OUT_CH; ++j) {
            const float lj = lg[j];
            rank += (lj > acc) || (lj == acc && j < o);
        }
        m_s[o] = (rank < NFILT) ? 1.0f : 0.0f;
    }
    __syncthreads();

    const int pos = chunk * 256 + threadIdx.x;
    const float4* x4 = reinterpret_cast<const float4*>(x);
    vfloat4*      o4 = reinterpret_cast<vfloat4*>(out);

    float4 xv[IN_CH];
    #pragma unroll
    for (int c = 0; c < IN_CH; ++c)
        xv[c] = x4[(size_t)(b * IN_CH + c) * HW4 + pos];

    for (int o = 0; o < OUT_CH; ++o) {
        vfloat4 r;
        if (m_s[o] != 0.0f) {
            const float bv = b_s[o];
            vfloat4 acc = {bv, bv, bv, bv};
            #pragma unroll
            for (int c = 0; c < IN_CH; ++c) {
                const float w = w_s[o][c];
                acc.x += w * xv[c].x;
                acc.y += w * xv[c].y;
                acc.z += w * xv[c].z;
                acc.w += w * xv[c].w;
            }
            r = acc;
        } else {
            r = (vfloat4){0.f, 0.f, 0.f, 0.f};
        }
        __builtin_nontemporal_store(r, &o4[(size_t)(b * OUT_CH + o) * HW4 + pos]);
    }
}

// ---------------------------------------------------------------------------
extern "C" void kernel_launch(void* const* d_in, const int* in_sizes, int n_in,
                              void* d_out, int out_size, void* d_ws, size_t ws_size,
                              hipStream_t stream) {
    const float* x    = (const float*)d_in[0];
    const float* w    = (const float*)d_in[1];
    const float* bias = (const float*)d_in[2];
    const float* rw   = (const float*)d_in[3];
    const float* rb   = (const float*)d_in[4];
    float* out = (float*)d_out;

    float* pooled = (float*)d_ws;  // BATCH*IN_CH floats

    pool_kernel<<<BATCH * IN_CH, 256, 0, stream>>>(x, pooled);
    conv_kernel<<<BATCH * CHUNKS, 256, 0, stream>>>(x, w, bias, rw, rb, pooled, out);
}

// Round 5
// 124.099 us; speedup vs baseline: 1.3014x; 1.0197x over previous
//
#include <hip/hip_runtime.h>

#define IN_CH   32
#define OUT_CH  64
#define NFILT   16
#define NINACT  (OUT_CH - NFILT)
#define BATCH   32
#define HW      50176     // 224*224
#define HW4     12544     // HW/4 (float4 elements per plane)
#define CHUNKS  49        // HW4 / 256

typedef float vfloat4 __attribute__((ext_vector_type(4)));

// ---------------------------------------------------------------------------
// Kernel 1: global average pool. One block per (b, c) plane; float4 loads,
// shuffle + LDS reduce. Caching loads on purpose: pulls x into the 256 MB
// Infinity Cache so the conv pass re-reads it from L3.
// ---------------------------------------------------------------------------
__global__ __launch_bounds__(256) void pool_kernel(const float* __restrict__ x,
                                                   float* __restrict__ pooled) {
    const int bc = blockIdx.x;
    const float4* xp = reinterpret_cast<const float4*>(x) + (size_t)bc * HW4;

    float4 s = make_float4(0.f, 0.f, 0.f, 0.f);
    for (int i = threadIdx.x; i < HW4; i += 256) {
        float4 v = xp[i];
        s.x += v.x; s.y += v.y; s.z += v.z; s.w += v.w;
    }
    float sum = (s.x + s.y) + (s.z + s.w);

    for (int off = 32; off > 0; off >>= 1)
        sum += __shfl_down(sum, off, 64);

    __shared__ float red[4];
    if ((threadIdx.x & 63) == 0) red[threadIdx.x >> 6] = sum;
    __syncthreads();
    if (threadIdx.x == 0) {
        float t = (red[0] + red[1]) + (red[2] + red[3]);
        pooled[bc] = t * (1.0f / (float)HW);
    }
}

// ---------------------------------------------------------------------------
// Kernel 2: fused router + 1x1 conv + bias + gate.
// Preamble: router logits for this block's sample -> rank-based top-16
// (jax tie-break: strictly greater, or equal with lower index). rank is the
// compaction index -> alist (16 active) / ilist (48 inactive).
// Body: issue 32 x-loads; burst 48 independent zero nt-stores (overlap the
// load latency with the write stream); then 16 active channels (bias + 32
// float4 FMAs each) with nt-stores. nt keeps the 411 MB output stream from
// evicting x out of Infinity Cache.
// ---------------------------------------------------------------------------
__global__ __launch_bounds__(256) void conv_kernel(const float* __restrict__ x,
                                                   const float* __restrict__ weight,
                                                   const float* __restrict__ bias,
                                                   const float* __restrict__ rw,
                                                   const float* __restrict__ rb,
                                                   const float* __restrict__ pooled,
                                                   float* __restrict__ out) {
    __shared__ float w_s[OUT_CH][IN_CH];
    __shared__ float b_s[OUT_CH];
    __shared__ float lg[OUT_CH];
    __shared__ unsigned char act[OUT_CH];
    __shared__ short alist[NFILT];
    __shared__ short ilist[NINACT];

    const int b     = blockIdx.x / CHUNKS;
    const int chunk = blockIdx.x % CHUNKS;

    for (int i = threadIdx.x; i < OUT_CH * IN_CH; i += 256)
        (&w_s[0][0])[i] = weight[i];

    if (threadIdx.x < OUT_CH) {
        const int o = threadIdx.x;
        b_s[o] = bias[o];
        float acc = rb[o];
        #pragma unroll
        for (int c = 0; c < IN_CH; ++c)
            acc += pooled[b * IN_CH + c] * rw[o * IN_CH + c];
        lg[o] = acc;
    }
    __syncthreads();

    if (threadIdx.x < OUT_CH) {
        const int o = threadIdx.x;
        const float v = lg[o];
        int rank = 0;
        #pragma unroll
        for (int j = 0; j < OUT_CH; ++j) {
            const float lj = lg[j];
            rank += (lj > v) || (lj == v && j < o);
        }
        const bool a = (rank < NFILT);
        act[o] = a;
        if (a) alist[rank] = (short)o;
    }
    __syncthreads();

    if (threadIdx.x < OUT_CH) {
        const int o = threadIdx.x;
        if (!act[o]) {
            int irank = 0;
            for (int j = 0; j < o; ++j) irank += !act[j];
            ilist[irank] = (short)o;
        }
    }
    __syncthreads();

    const int pos = chunk * 256 + threadIdx.x;
    const float4* x4 = reinterpret_cast<const float4*>(x);
    vfloat4*      o4 = reinterpret_cast<vfloat4*>(out);

    // issue all 32 channel loads (stay in flight during the zero burst)
    float4 xv[IN_CH];
    #pragma unroll
    for (int c = 0; c < IN_CH; ++c)
        xv[c] = x4[(size_t)(b * IN_CH + c) * HW4 + pos];

    // zero burst: 48 independent nt-stores, no load dependency
    const vfloat4 z = {0.f, 0.f, 0.f, 0.f};
    #pragma unroll
    for (int k = 0; k < NINACT; ++k) {
        const int o = ilist[k];
        __builtin_nontemporal_store(z, &o4[(size_t)(b * OUT_CH + o) * HW4 + pos]);
    }

    // active channels
    #pragma unroll
    for (int k = 0; k < NFILT; ++k) {
        const int o = alist[k];
        const float bv = b_s[o];
        vfloat4 r = {bv, bv, bv, bv};
        #pragma unroll
        for (int c = 0; c < IN_CH; ++c) {
            const float w = w_s[o][c];
            r.x += w * xv[c].x;
            r.y += w * xv[c].y;
            r.z += w * xv[c].z;
            r.w += w * xv[c].w;
        }
        __builtin_nontemporal_store(r, &o4[(size_t)(b * OUT_CH + o) * HW4 + pos]);
    }
}

// ---------------------------------------------------------------------------
extern "C" void kernel_launch(void* const* d_in, const int* in_sizes, int n_in,
                              void* d_out, int out_size, void* d_ws, size_t ws_size,
                              hipStream_t stream) {
    const float* x    = (const float*)d_in[0];
    const float* w    = (const float*)d_in[1];
    const float* bias = (const float*)d_in[2];
    const float* rw   = (const float*)d_in[3];
    const float* rb   = (const float*)d_in[4];
    float* out    = (float*)d_out;
    float* pooled = (float*)d_ws;  // BATCH*IN_CH floats

    pool_kernel<<<BATCH * IN_CH, 256, 0, stream>>>(x, pooled);
    conv_kernel<<<BATCH * CHUNKS, 256, 0, stream>>>(x, w, bias, rw, rb, pooled, out);
}